// Round 1
// baseline (402.770 us; speedup 1.0000x reference)
//
#include <hip/hip_runtime.h>

typedef __bf16 bf16_t;
typedef __bf16 bf16x8 __attribute__((ext_vector_type(8)));
typedef float f32x4 __attribute__((ext_vector_type(4)));

#define B_TOTAL 262144
#define OUTC 324

// d_ws layout (bf16 element offsets)
#define OFF_WIN   0        // [64][32]
#define OFF_WG    2048     // [256][256] gate-major: n = g*64 + j
#define OFF_WM1   67584    // [4][112][64]
#define OFF_WM2   96256    // [4][32][128]
#define OFF_WU1   112640   // [112][64]
#define OFF_WU2   119808   // [112][128]
#define OFF_WU3   134144   // [64][128]
#define OFF_WMV   142336   // [32][64]  (mu rows 0:16, var rows 16:32)
#define BF16_TOTAL 144384
// f32 combined gate bias bg[256] lives at byte offset BF16_TOTAL*2

__global__ void prep_kernel(const float* W_in, const float* msg_W1, const float* msg_W2,
                            const float* W_ih, const float* W_hh, const float* b_ih, const float* b_hh,
                            const float* W_u1, const float* W_u2, const float* W_u3,
                            const float* W_mu, const float* W_var,
                            bf16_t* wb, float* bg) {
  int tid = blockIdx.x * blockDim.x + threadIdx.x;
  int nth = gridDim.x * blockDim.x;
  for (int i = tid; i < 2048; i += nth) wb[OFF_WIN + i] = (bf16_t)W_in[i];
  for (int i = tid; i < 65536; i += nth) {
    int n = i >> 8, k = i & 255;
    int g = n >> 6, j = n & 63;
    float v = 0.f;
    if (j < 50) {
      int r = g * 50 + j;
      if (k < 192) v = W_ih[r * 192 + k];
      else if (k < 242) v = W_hh[r * 50 + (k - 192)];
    }
    wb[OFF_WG + i] = (bf16_t)v;
  }
  for (int i = tid; i < 256; i += nth) {
    int g = i >> 6, j = i & 63;
    bg[i] = (j < 50) ? (b_ih[g * 50 + j] + b_hh[g * 50 + j]) : 0.f;
  }
  for (int i = tid; i < 4 * 112 * 64; i += nth) {
    int p = i / (112 * 64); int rem = i % (112 * 64); int n = rem >> 6, k = rem & 63;
    wb[OFF_WM1 + i] = (bf16_t)((n < 100) ? msg_W1[(p * 100 + n) * 64 + k] : 0.f);
  }
  for (int i = tid; i < 4 * 32 * 128; i += nth) {
    int p = i / (32 * 128); int rem = i % (32 * 128); int n = rem >> 7, k = rem & 127;
    wb[OFF_WM2 + i] = (bf16_t)((k < 100) ? msg_W2[(p * 32 + n) * 100 + k] : 0.f);
  }
  for (int i = tid; i < 112 * 64; i += nth) {
    int n = i >> 6, k = i & 63;
    wb[OFF_WU1 + i] = (bf16_t)((n < 100 && k < 50) ? W_u1[n * 50 + k] : 0.f);
  }
  for (int i = tid; i < 112 * 128; i += nth) {
    int n = i >> 7, k = i & 127;
    wb[OFF_WU2 + i] = (bf16_t)((n < 100 && k < 100) ? W_u2[n * 100 + k] : 0.f);
  }
  for (int i = tid; i < 64 * 128; i += nth) {
    int n = i >> 7, k = i & 127;
    wb[OFF_WU3 + i] = (bf16_t)((k < 100) ? W_u3[n * 100 + k] : 0.f);
  }
  for (int i = tid; i < 32 * 64; i += nth) {
    int n = i >> 6, k = i & 63;
    wb[OFF_WMV + i] = (bf16_t)((n < 16) ? W_mu[n * 64 + k] : W_var[(n - 16) * 64 + k]);
  }
}

template <int KS>
__device__ __forceinline__ f32x4 mm_tile(const bf16_t* A, int lda,
                                         const bf16_t* Bw, int ldb,
                                         f32x4 acc, int lr, int kq) {
  const bf16_t* ap = A + lr * lda + kq * 8;
  const bf16_t* bp = Bw + lr * ldb + kq * 8;
#pragma unroll
  for (int k = 0; k < KS; k++) {
    bf16x8 a = *(const bf16x8*)(ap + k * 32);
    bf16x8 b = *(const bf16x8*)(bp + k * 32);
    acc = __builtin_amdgcn_mfma_f32_16x16x32_bf16(a, b, acc, 0, 0, 0);
  }
  return acc;
}

__device__ __forceinline__ float softplus_f(float x) {
  return (x > 20.f) ? x : log1pf(expf(x));
}

// LDS strides (elements): hm 264 (rows of 256+8 pad), t1 136 (128+8), hn 72 (64+8)
__global__ __launch_bounds__(256, 2) void fused_kernel(
    const float* __restrict__ obs, const float* __restrict__ msg_in,
    const float* __restrict__ h_lstm, const float* __restrict__ c_lstm,
    const float* __restrict__ b_in, const float* __restrict__ msg_b1,
    const float* __restrict__ msg_b2, const float* __restrict__ b_u1,
    const float* __restrict__ b_u2, const float* __restrict__ b_u3,
    const float* __restrict__ b_mu, const float* __restrict__ b_var,
    const float* __restrict__ maxlv, const float* __restrict__ minlv,
    const bf16_t* __restrict__ wb, const float* __restrict__ bg,
    float* __restrict__ out) {
  __shared__ __align__(16) bf16_t hm[64 * 264];  // cols: 0:64 x | 64:192 agg->h2b | 192:242 h_lstm | 242:256 zero
  __shared__ __align__(16) bf16_t t1[64 * 136];  // obs_l(overlay) -> m1 -> h2a -> h2
  __shared__ __align__(16) bf16_t hn[64 * 72];   // h_new padded to 64

  const int tid = threadIdx.x;
  const int row0 = blockIdx.x * 64;
  const int lane = tid & 63;
  const int wave = tid >> 6;
  const int lr = lane & 15;
  const int kq = lane >> 4;
  bf16_t* obs_l = t1;  // stride 40

  // ---- Stage 0: stage inputs into LDS as bf16 ----
  {
    int base = tid * 8;
    int row = base >> 5, col = base & 31;
    const float4* s = (const float4*)(obs + (size_t)row0 * 32 + base);
    float4 v0 = s[0], v1 = s[1];
    bf16_t* d = obs_l + row * 40 + col;
    d[0] = (bf16_t)v0.x; d[1] = (bf16_t)v0.y; d[2] = (bf16_t)v0.z; d[3] = (bf16_t)v0.w;
    d[4] = (bf16_t)v1.x; d[5] = (bf16_t)v1.y; d[6] = (bf16_t)v1.z; d[7] = (bf16_t)v1.w;
  }
#pragma unroll
  for (int p = 0; p < 4; p++) {
    int base = tid * 8;
    int row = base >> 5, m = base & 31;
    const float4* s = (const float4*)(msg_in + (size_t)p * B_TOTAL * 32 + (size_t)row0 * 32 + base);
    float4 v0 = s[0], v1 = s[1];
    bf16_t* d = hm + row * 264 + 64 + p * 32 + m;
    d[0] = (bf16_t)v0.x; d[1] = (bf16_t)v0.y; d[2] = (bf16_t)v0.z; d[3] = (bf16_t)v0.w;
    d[4] = (bf16_t)v1.x; d[5] = (bf16_t)v1.y; d[6] = (bf16_t)v1.z; d[7] = (bf16_t)v1.w;
  }
  {
    int base = tid * 16;
    int row = base >> 6, c0 = base & 63;
    const float* s = h_lstm + (size_t)(row0 + row) * 50;
    bf16_t* d = hm + row * 264 + 192;
#pragma unroll
    for (int i = 0; i < 16; i++) {
      int c = c0 + i;
      d[c] = (bf16_t)((c < 50) ? s[c] : 0.f);
    }
  }
  __syncthreads();

  // ---- Stage 1: x = relu(obs @ W_in^T + b_in) -> hm[:,0:64] ----
  {
    int nb = wave * 16;
    float bv = b_in[nb + lr];
    const bf16_t* Bw = wb + OFF_WIN + nb * 32;
#pragma unroll
    for (int m = 0; m < 4; m++) {
      f32x4 acc = {bv, bv, bv, bv};
      acc = mm_tile<1>(obs_l + m * 16 * 40, 40, Bw, 32, acc, lr, kq);
#pragma unroll
      for (int rr = 0; rr < 4; rr++) {
        float v = acc[rr]; v = v > 0.f ? v : 0.f;
        hm[(m * 16 + kq * 4 + rr) * 264 + nb + lr] = (bf16_t)v;
      }
    }
  }
  __syncthreads();

  // zero t1 pad cols 112:128 (obs_l overlay is dead now); completes before the S3 sync
  {
    int idx = tid * 4;
    int row = idx >> 4;
    int cc = 112 + (idx & 15);
#pragma unroll
    for (int q = 0; q < 4; q++) t1[row * 136 + cc + q] = (bf16_t)0.f;
  }

  // ---- Stages 2/3 per port: m1 = relu(x@W1^T) ; msgs = m1@W2^T -> out ----
  for (int p = 0; p < 4; p++) {
    for (int nt = wave; nt < 7; nt += 4) {
      int nb = nt * 16;
      float bv = (nb + lr < 100) ? msg_b1[p * 100 + nb + lr] : 0.f;
      const bf16_t* Bw = wb + OFF_WM1 + p * 112 * 64 + nb * 64;
#pragma unroll
      for (int m = 0; m < 4; m++) {
        f32x4 acc = {bv, bv, bv, bv};
        acc = mm_tile<2>(hm + m * 16 * 264, 264, Bw, 64, acc, lr, kq);
#pragma unroll
        for (int rr = 0; rr < 4; rr++) {
          float v = acc[rr]; v = v > 0.f ? v : 0.f;
          t1[(m * 16 + kq * 4 + rr) * 136 + nb + lr] = (bf16_t)v;
        }
      }
    }
    __syncthreads();
#pragma unroll
    for (int nt = 0; nt < 2; nt++) {
      int nb = nt * 16;
      int m = wave;
      float bv = msg_b2[p * 32 + nb + lr];
      const bf16_t* Bw = wb + OFF_WM2 + p * 32 * 128 + nb * 128;
      f32x4 acc = {bv, bv, bv, bv};
      acc = mm_tile<4>(t1 + m * 16 * 136, 136, Bw, 128, acc, lr, kq);
#pragma unroll
      for (int rr = 0; rr < 4; rr++) {
        int row = row0 + m * 16 + kq * 4 + rr;
        out[(size_t)row * OUTC + 32 + p * 32 + nb + lr] = acc[rr];
      }
    }
    __syncthreads();
  }

  // ---- Stage 4: gates + LSTM cell. wave w owns j in [16w,16w+16) of all 4 gates ----
  {
    const bf16_t* Bg = wb + OFF_WG;
    const int nbase = wave * 16 + lr;  // j
    bf16x8 Bf0[8], Bf1[8], Bf2[8], Bf3[8];
#pragma unroll
    for (int k = 0; k < 8; k++) {
      Bf0[k] = *(const bf16x8*)(Bg + (0 * 64 + nbase) * 256 + kq * 8 + k * 32);
      Bf1[k] = *(const bf16x8*)(Bg + (1 * 64 + nbase) * 256 + kq * 8 + k * 32);
      Bf2[k] = *(const bf16x8*)(Bg + (2 * 64 + nbase) * 256 + kq * 8 + k * 32);
      Bf3[k] = *(const bf16x8*)(Bg + (3 * 64 + nbase) * 256 + kq * 8 + k * 32);
    }
    float bv0 = bg[nbase], bv1 = bg[64 + nbase], bv2 = bg[128 + nbase], bv3 = bg[192 + nbase];
    const int j = nbase;
#pragma unroll
    for (int m = 0; m < 4; m++) {
      bf16x8 Af[8];
#pragma unroll
      for (int k = 0; k < 8; k++)
        Af[k] = *(const bf16x8*)(hm + (m * 16 + lr) * 264 + kq * 8 + k * 32);
      f32x4 ai = {bv0, bv0, bv0, bv0}, af = {bv1, bv1, bv1, bv1};
      f32x4 ag = {bv2, bv2, bv2, bv2}, ao = {bv3, bv3, bv3, bv3};
#pragma unroll
      for (int k = 0; k < 8; k++) {
        ai = __builtin_amdgcn_mfma_f32_16x16x32_bf16(Af[k], Bf0[k], ai, 0, 0, 0);
        af = __builtin_amdgcn_mfma_f32_16x16x32_bf16(Af[k], Bf1[k], af, 0, 0, 0);
        ag = __builtin_amdgcn_mfma_f32_16x16x32_bf16(Af[k], Bf2[k], ag, 0, 0, 0);
        ao = __builtin_amdgcn_mfma_f32_16x16x32_bf16(Af[k], Bf3[k], ao, 0, 0, 0);
      }
#pragma unroll
      for (int rr = 0; rr < 4; rr++) {
        int lrow = m * 16 + kq * 4 + rr;
        int row = row0 + lrow;
        float iv = ai[rr], fv = af[rr], gv = ag[rr], ov = ao[rr];
        float c_old = 0.f;
        if (j < 50) c_old = c_lstm[(size_t)row * 50 + j];
        float si = 1.f / (1.f + expf(-iv));
        float sf = 1.f / (1.f + expf(-fv));
        float so = 1.f / (1.f + expf(-ov));
        float cn = sf * c_old + si * tanhf(gv);
        float hv = so * tanhf(cn);
        if (j < 50) {
          out[(size_t)row * OUTC + 274 + j] = cn;
          out[(size_t)row * OUTC + 224 + j] = hv;
        }
        hn[lrow * 72 + j] = (bf16_t)((j < 50) ? hv : 0.f);
      }
    }
  }
  __syncthreads();

  // zero hm cols 176:192 (pad region for h2b, old agg data) — hm unused by S6
  {
    int idx = tid * 4;
    int row = idx >> 4;
    int cc = 176 + (idx & 15);
#pragma unroll
    for (int q = 0; q < 4; q++) hm[row * 264 + cc + q] = (bf16_t)0.f;
  }

  // ---- Stage 6: h2a = relu(h_new @ W_u1^T + b_u1) -> t1[:,0:112] ----
  for (int nt = wave; nt < 7; nt += 4) {
    int nb = nt * 16;
    float bv = (nb + lr < 100) ? b_u1[nb + lr] : 0.f;
    const bf16_t* Bw = wb + OFF_WU1 + nb * 64;
#pragma unroll
    for (int m = 0; m < 4; m++) {
      f32x4 acc = {bv, bv, bv, bv};
      acc = mm_tile<2>(hn + m * 16 * 72, 72, Bw, 64, acc, lr, kq);
#pragma unroll
      for (int rr = 0; rr < 4; rr++) {
        float v = acc[rr]; v = v > 0.f ? v : 0.f;
        t1[(m * 16 + kq * 4 + rr) * 136 + nb + lr] = (bf16_t)v;
      }
    }
  }
  __syncthreads();

  // ---- Stage 7: h2b = relu(h2a @ W_u2^T + b_u2) -> hm[:,64:176] ----
  for (int nt = wave; nt < 7; nt += 4) {
    int nb = nt * 16;
    float bv = (nb + lr < 100) ? b_u2[nb + lr] : 0.f;
    const bf16_t* Bw = wb + OFF_WU2 + nb * 128;
#pragma unroll
    for (int m = 0; m < 4; m++) {
      f32x4 acc = {bv, bv, bv, bv};
      acc = mm_tile<4>(t1 + m * 16 * 136, 136, Bw, 128, acc, lr, kq);
#pragma unroll
      for (int rr = 0; rr < 4; rr++) {
        float v = acc[rr]; v = v > 0.f ? v : 0.f;
        hm[(m * 16 + kq * 4 + rr) * 264 + 64 + nb + lr] = (bf16_t)v;
      }
    }
  }
  __syncthreads();

  // ---- Stage 8: h2 = h2b @ W_u3^T + b_u3 -> out[:,160:224] and t1[:,0:64] ----
  {
    int nb = wave * 16;
    float bv = b_u3[nb + lr];
    const bf16_t* Bw = wb + OFF_WU3 + nb * 128;
#pragma unroll
    for (int m = 0; m < 4; m++) {
      f32x4 acc = {bv, bv, bv, bv};
      acc = mm_tile<4>(hm + m * 16 * 264 + 64, 264, Bw, 128, acc, lr, kq);
#pragma unroll
      for (int rr = 0; rr < 4; rr++) {
        int lrow = m * 16 + kq * 4 + rr;
        int row = row0 + lrow;
        float v = acc[rr];
        out[(size_t)row * OUTC + 160 + nb + lr] = v;
        t1[lrow * 136 + nb + lr] = (bf16_t)v;
      }
    }
  }
  __syncthreads();

  // ---- Stage 9: mu / var heads (each wave handles its own m-tile, both n-tiles) ----
  {
    int m = wave;
    const bf16_t* Ab = t1 + m * 16 * 136;
    {
      float bv = b_mu[lr];
      f32x4 acc = {bv, bv, bv, bv};
      acc = mm_tile<2>(Ab, 136, wb + OFF_WMV, 64, acc, lr, kq);
#pragma unroll
      for (int rr = 0; rr < 4; rr++) {
        int row = row0 + m * 16 + kq * 4 + rr;
        out[(size_t)row * OUTC + lr] = acc[rr];
      }
    }
    {
      float bv = b_var[lr];
      f32x4 acc = {bv, bv, bv, bv};
      acc = mm_tile<2>(Ab, 136, wb + OFF_WMV + 16 * 64, 64, acc, lr, kq);
      float mx = maxlv[lr], mn = minlv[lr];
#pragma unroll
      for (int rr = 0; rr < 4; rr++) {
        int row = row0 + m * 16 + kq * 4 + rr;
        float lv = acc[rr];
        lv = mx - softplus_f(mx - lv);
        lv = mn + softplus_f(lv - mn);
        out[(size_t)row * OUTC + 16 + lr] = expf(lv);
      }
    }
  }
}

extern "C" void kernel_launch(void* const* d_in, const int* in_sizes, int n_in,
                              void* d_out, int out_size, void* d_ws, size_t ws_size,
                              hipStream_t stream) {
  const float* obs   = (const float*)d_in[0];
  const float* msgs  = (const float*)d_in[1];
  const float* h_l   = (const float*)d_in[2];
  const float* c_l   = (const float*)d_in[3];
  const float* W_in  = (const float*)d_in[4];
  const float* b_in  = (const float*)d_in[5];
  const float* mW1   = (const float*)d_in[6];
  const float* mb1   = (const float*)d_in[7];
  const float* mW2   = (const float*)d_in[8];
  const float* mb2   = (const float*)d_in[9];
  const float* W_ih  = (const float*)d_in[10];
  const float* W_hh  = (const float*)d_in[11];
  const float* b_ih  = (const float*)d_in[12];
  const float* b_hh  = (const float*)d_in[13];
  const float* W_u1  = (const float*)d_in[14];
  const float* b_u1  = (const float*)d_in[15];
  const float* W_u2  = (const float*)d_in[16];
  const float* b_u2  = (const float*)d_in[17];
  const float* W_u3  = (const float*)d_in[18];
  const float* b_u3  = (const float*)d_in[19];
  const float* W_mu  = (const float*)d_in[20];
  const float* b_mu  = (const float*)d_in[21];
  const float* W_var = (const float*)d_in[22];
  const float* b_var = (const float*)d_in[23];
  const float* maxlv = (const float*)d_in[24];
  const float* minlv = (const float*)d_in[25];

  bf16_t* wb = (bf16_t*)d_ws;
  float* bg = (float*)((char*)d_ws + (size_t)BF16_TOTAL * 2);

  prep_kernel<<<64, 256, 0, stream>>>(W_in, mW1, mW2, W_ih, W_hh, b_ih, b_hh,
                                      W_u1, W_u2, W_u3, W_mu, W_var, wb, bg);
  fused_kernel<<<B_TOTAL / 64, 256, 0, stream>>>(
      obs, msgs, h_l, c_l, b_in, mb1, mb2, b_u1, b_u2, b_u3,
      b_mu, b_var, maxlv, minlv, wb, bg, (float*)d_out);
}